// Round 12
// baseline (175.702 us; speedup 1.0000x reference)
//
#include <hip/hip_runtime.h>
#include <hip/hip_fp16.h>

typedef __attribute__((ext_vector_type(8)))  _Float16 half8v;  // 8 f16 = 4 VGPR
typedef __attribute__((ext_vector_type(16))) float    f32x16;

// bswz step layout (512 f16 per step, real steps only — node term moved to segsum):
//  L0 [0,17)   L1 [17,83)   L2 [83,149)   L3 [149,215)
static constexpr int BSWZ_STEPS = 215;
static constexpr int BSWZ_TOT   = BSWZ_STEPS * 512;   // 110080 f16

struct Prm {
    const float* x;
    const float* w2[4]; const float* b2[4];
    _Float16* xin;    // N x 8 f16 (x[:,4:10], zero-padded)
    _Float16* bswz;
    int* cnt;         // N ints, zeroed here (histogram -> cursor)
    int N;
};

// ---------------------------------------------------------------------------
// prep: [0,430) build bswz ; [430,430+NB8) pack xin ; [.., +NBC) zero cnt.
// ---------------------------------------------------------------------------
__global__ __launch_bounds__(256) void prep(Prm p, int NB8, int NBC)
{
    int b = blockIdx.x;
    if (b < 430) {                                   // ---- bswz ----
        int i = b * 256 + threadIdx.x;               // < 110080 exactly
        int T = i >> 9, t2 = i & 511;
        int j = t2 & 7, l = (t2 >> 3) & 63;
        int g = l >> 5, o = l & 31;
        int layer, t;
        if (T < 17)       { layer = 0; t = T; }
        else if (T < 83)  { layer = 1; t = T - 17; }
        else if (T < 149) { layer = 2; t = T - 83; }
        else              { layer = 3; t = T - 149; }
        const int INP   = (layer == 0) ? 8 : 32;
        const int IN_C  = (layer == 0) ? 6 : 32;
        const int OUT_C = (layer == 3) ? 2 : 32;
        const int S_MAIN = 2 * INP;
        float v = 0.f;
        if (t < S_MAIN) {
            int kap = 16 * t + 8 * g + j;
            int k  = (INP == 8) ? (kap >> 3) : (kap >> 5);
            int ii = (INP == 8) ? (kap & 7)  : (kap & 31);
            if (ii < IN_C && o < OUT_C)
                v = p.w2[layer][(size_t)k * (IN_C * OUT_C) + ii * OUT_C + o];
        } else {
            int ii = 16 * (t - S_MAIN) + 8 * g + j;
            if (ii < IN_C && o < OUT_C)
                v = p.b2[layer][ii * OUT_C + o];
        }
        p.bswz[i] = (_Float16)v;
    } else if (b < 430 + NB8) {                      // ---- pack xin ----
        int i = (b - 430) * 256 + threadIdx.x;
        if (i < p.N * 8) {
            int v = i >> 3, c = i & 7;
            float val = (c < 6) ? p.x[(size_t)v * 10 + 4 + c] : 0.f;
            p.xin[i] = (_Float16)val;
        }
    } else {                                         // ---- zero cnt ----
        int i = (b - 430 - NB8) * 256 + threadIdx.x;
        if (i < p.N) p.cnt[i] = 0;
    }
}

// ---------------------------------------------------------------------------
// CSR build (amortized over all 4 layers).
// ---------------------------------------------------------------------------
__global__ __launch_bounds__(256) void hist(
    const int* __restrict__ dst, int* __restrict__ cnt, int E)
{
    int e = blockIdx.x * 256 + threadIdx.x;
    if (e < E) atomicAdd(&cnt[dst[e]], 1);
}

__global__ __launch_bounds__(256) void scan_part(
    const int* __restrict__ cnt, int* __restrict__ bsum, int N)
{
    __shared__ int lds[256];
    int i = blockIdx.x * 256 + threadIdx.x;
    int v = (i < N) ? cnt[i] : 0;
    lds[threadIdx.x] = v;
    __syncthreads();
    #pragma unroll
    for (int off = 128; off > 0; off >>= 1) {
        if (threadIdx.x < off) lds[threadIdx.x] += lds[threadIdx.x + off];
        __syncthreads();
    }
    if (threadIdx.x == 0) bsum[blockIdx.x] = lds[0];
}

// final: inline prefix over bsum (each block sums bsum[0..b)) + local scan
__global__ __launch_bounds__(256) void scan_final(
    int* __restrict__ cnt, const int* __restrict__ bsum,
    int* __restrict__ rowptr, int N)
{
    __shared__ int lds[256];
    __shared__ int pref;
    const int b = blockIdx.x;
    int s = 0;
    for (int j = threadIdx.x; j < b; j += 256) s += bsum[j];
    lds[threadIdx.x] = s;
    __syncthreads();
    #pragma unroll
    for (int off = 128; off > 0; off >>= 1) {
        if (threadIdx.x < off) lds[threadIdx.x] += lds[threadIdx.x + off];
        __syncthreads();
    }
    if (threadIdx.x == 0) pref = lds[0];
    __syncthreads();
    int i = (b << 8) + threadIdx.x;
    int v = (i < N) ? cnt[i] : 0;
    lds[threadIdx.x] = v;
    __syncthreads();
    for (int off = 1; off < 256; off <<= 1) {        // inclusive Hillis-Steele
        int u = (threadIdx.x >= off) ? lds[threadIdx.x - off] : 0;
        __syncthreads();
        lds[threadIdx.x] += u;
        __syncthreads();
    }
    int excl = lds[threadIdx.x] - v + pref;
    if (i < N) {
        rowptr[i] = excl;
        cnt[i] = excl;                               // scatter cursor
        if (i == N - 1) rowptr[N] = excl + v;
    }
}

__global__ __launch_bounds__(256) void scatter(
    const int* __restrict__ src, const int* __restrict__ dst,
    const float* __restrict__ ea, int* __restrict__ cursor,
    int* __restrict__ srcP, float* __restrict__ eaP, int E)
{
    int e = blockIdx.x * 256 + threadIdx.x;
    if (e >= E) return;
    int pos = atomicAdd(&cursor[dst[e]], 1);
    srcP[pos] = src[e];
    ((float4*)eaP)[pos] = ((const float4*)ea)[e];
}

// gather 32 f16 feats for node s, relu in packed f16
static __device__ __forceinline__ void gather32h(
    const _Float16* __restrict__ fprev, int s, int g, half8v& xh0, half8v& xh1)
{
    const half8v* fp = (const half8v*)(fprev + (size_t)s * 32);
    xh0 = fp[g];
    xh1 = fp[2 + g];
    #pragma unroll
    for (int j = 0; j < 8; ++j) {
        xh0[j] = xh0[j] > (_Float16)0.f ? xh0[j] : (_Float16)0.f;
        xh1[j] = xh1[j] > (_Float16)0.f ? xh1[j] : (_Float16)0.f;
    }
}

// ---------------------------------------------------------------------------
// Edge kernel: wave = 32 dst-sorted edges; LDS-staged B; NO atomics — msg
// written with plain coalesced half2 stores in sorted order.
// C layout: col = lane&31 = o, row = (r&3)+8*(r>>2)+4*(lane>>5).
// ---------------------------------------------------------------------------
template<int INP, int OUT_C>
__global__ __launch_bounds__(512) void edge(
    const _Float16* __restrict__ xin,     // layer0 features (N x 8)
    const _Float16* __restrict__ fprev,   // mid features (N x 32 f16, pre-relu)
    const int*      __restrict__ srcP,    // dst-sorted
    const float*    __restrict__ eaP,     // dst-sorted
    const float*    __restrict__ w1,      // (4,32) row-major
    const float*    __restrict__ b1,      // (32)
    const _Float16* __restrict__ bAll,
    _Float16* __restrict__ msg,           // E x OUT_C f16, dst-sorted
    int E, int ntileE)
{
    constexpr int NSTEP = (INP == 32) ? 66 : 17;

    __shared__ half8v ldsb[NSTEP * 64];
    {
        const half8v* bp = (const half8v*)bAll;
        for (int i = threadIdx.x; i < NSTEP * 64; i += 512)
            ldsb[i] = bp[i];
    }
    __syncthreads();

    const int lane = threadIdx.x & 63;
    const int g = lane >> 5, o = lane & 31;
    const int lrow = lane & 31;
    const int wv = (blockIdx.x * 512 + threadIdx.x) >> 6;
    const int nw = gridDim.x * 8;

    for (int tile = wv; tile < ntileE; tile += nw) {
        const int e0 = tile * 32;
        const int er = e0 + lrow;
        const int ec = er < E ? er : (E - 1);
        const int s  = srcP[ec];
        const float4 av = *(const float4*)(eaP + 4ll * ec);

        half8v xh0, xh1;
        if constexpr (INP == 32) gather32h(fprev, s, g, xh0, xh1);
        else                     xh0 = *(const half8v*)(xin + (size_t)s * 8);

        f32x16 C;
        #pragma unroll
        for (int i = 0; i < 16; ++i) C[i] = 0.f;

        if constexpr (INP == 32) {
            #pragma unroll 4
            for (int k = 0; k < 32; ++k) {
                half8v bf0 = ldsb[(2*k    ) * 64 + lane];
                half8v bf1 = ldsb[(2*k + 1) * 64 + lane];
                float hk = fmaf(av.x, w1[k], b1[k]);
                hk = fmaf(av.y, w1[32 + k], hk);
                hk = fmaf(av.z, w1[64 + k], hk);
                hk = fmaf(av.w, w1[96 + k], hk);
                hk = fmaxf(hk, 0.f);
                const _Float16 hh = (_Float16)hk;
                half8v hs;
                #pragma unroll
                for (int j = 0; j < 8; ++j) hs[j] = hh;
                C = __builtin_amdgcn_mfma_f32_32x32x16_f16(hs * xh0, bf0, C, 0, 0, 0);
                C = __builtin_amdgcn_mfma_f32_32x32x16_f16(hs * xh1, bf1, C, 0, 0, 0);
            }
            C = __builtin_amdgcn_mfma_f32_32x32x16_f16(xh0, ldsb[64*64 + lane], C, 0, 0, 0);
            C = __builtin_amdgcn_mfma_f32_32x32x16_f16(xh1, ldsb[65*64 + lane], C, 0, 0, 0);
        } else {
            #pragma unroll 4
            for (int t = 0; t < 16; ++t) {
                half8v bf = ldsb[t * 64 + lane];
                const int k = 2 * t + g;              // lane-dependent
                float hk = fmaf(av.x, w1[k], b1[k]);
                hk = fmaf(av.y, w1[32 + k], hk);
                hk = fmaf(av.z, w1[64 + k], hk);
                hk = fmaf(av.w, w1[96 + k], hk);
                hk = fmaxf(hk, 0.f);
                const _Float16 hh = (_Float16)hk;
                half8v hs;
                #pragma unroll
                for (int j = 0; j < 8; ++j) hs[j] = hh;
                C = __builtin_amdgcn_mfma_f32_32x32x16_f16(hs * xh0, bf, C, 0, 0, 0);
            }
            half8v zz;
            #pragma unroll
            for (int j = 0; j < 8; ++j) zz[j] = (_Float16)0.f;
            half8v a = (g == 0) ? xh0 : zz;           // b2 tail
            C = __builtin_amdgcn_mfma_f32_32x32x16_f16(a, ldsb[16*64 + lane], C, 0, 0, 0);
        }

        // msg store: pair lanes (o, o^1) -> one half2 per C element, even lane
        const bool full = (e0 + 31 < E);
        #pragma unroll
        for (int q = 0; q < 4; ++q) {
            #pragma unroll
            for (int m = 0; m < 4; ++m) {
                const int row = e0 + 8*q + 4*g + m;
                float mine = C[4*q + m];
                float oth  = __shfl_xor(mine, 1);
                if constexpr (OUT_C == 32) {
                    if (!(o & 1) && (full || row < E))
                        *(__half2*)(msg + (size_t)row * 32 + o) =
                            __floats2half2_rn(mine, oth);
                } else {
                    if (o == 0 && (full || row < E))
                        *(__half2*)(msg + (size_t)row * 2) =
                            __floats2half2_rn(mine, oth);
                }
            }
        }
    }
}

// ---------------------------------------------------------------------------
// segsum: out[v] = bias + relu?(fprev[v]) @ root + sum of msg rows
// rowptr[v]..rowptr[v+1] (accumulated in f32).  Thread = (node, 8-col chunk).
// OUT_C==32 -> agg f16 (pre-relu).  OUT_C==2 -> d_out f32.
// ---------------------------------------------------------------------------
template<int IN_C, int OUT_C>
__global__ __launch_bounds__(256) void segsum(
    const _Float16* __restrict__ fprev,   // xin (IN_C=6, stride 8) or agg (32)
    const _Float16* __restrict__ msg,
    const int*      __restrict__ rowptr,
    const float*    __restrict__ root,
    const float*    __restrict__ bias,
    _Float16* __restrict__ aggOut,        // OUT_C==32
    float*    __restrict__ outF,          // OUT_C==2
    int N)
{
    constexpr int CH = (OUT_C >= 8) ? 8 : OUT_C;
    constexpr int NC = OUT_C / CH;
    int tid = blockIdx.x * 256 + threadIdx.x;
    int v = tid / NC, c = tid % NC;
    if (v >= N) return;
    const int c0 = c * CH;

    float acc[CH];
    #pragma unroll
    for (int j = 0; j < CH; ++j) acc[j] = bias[c0 + j];

    if constexpr (IN_C == 6) {
        half8v u = *(const half8v*)(fprev + (size_t)v * 8);
        #pragma unroll
        for (int i = 0; i < 6; ++i) {
            float xi = (float)u[i];                   // layer0: no relu
            #pragma unroll
            for (int j = 0; j < CH; ++j)
                acc[j] = fmaf(xi, root[i * OUT_C + c0 + j], acc[j]);
        }
    } else {
        const half8v* fp = (const half8v*)(fprev + (size_t)v * 32);
        #pragma unroll
        for (int blk = 0; blk < 4; ++blk) {
            half8v u = fp[blk];
            #pragma unroll
            for (int jj = 0; jj < 8; ++jj) {
                float xi = fmaxf((float)u[jj], 0.f);
                int i = blk * 8 + jj;
                #pragma unroll
                for (int j = 0; j < CH; ++j)
                    acc[j] = fmaf(xi, root[i * OUT_C + c0 + j], acc[j]);
            }
        }
    }

    const int r1 = rowptr[v + 1];
    for (int r = rowptr[v]; r < r1; ++r) {
        if constexpr (OUT_C == 32) {
            half8v u = *(const half8v*)(msg + (size_t)r * 32 + c0);
            #pragma unroll
            for (int j = 0; j < CH; ++j) acc[j] += (float)u[j];
        } else {
            __half2 u = *(const __half2*)(msg + (size_t)r * 2);
            float2 f = __half22float2(u);
            acc[0] += f.x; acc[1] += f.y;
        }
    }

    if constexpr (OUT_C == 32) {
        half8v u;
        #pragma unroll
        for (int j = 0; j < CH; ++j) u[j] = (_Float16)acc[j];   // pre-relu
        *(half8v*)(aggOut + (size_t)v * 32 + c0) = u;
    } else {
        float2 o2; o2.x = acc[0]; o2.y = acc[1];
        ((float2*)outF)[v] = o2;
    }
}

// ---------------------------------------------------------------------------
extern "C" void kernel_launch(void* const* d_in, const int* in_sizes, int n_in,
                              void* d_out, int out_size, void* d_ws, size_t ws_size,
                              hipStream_t stream)
{
    const float* x  = (const float*)d_in[0];
    const int*   ei = (const int*)d_in[1];
    const float* ea = (const float*)d_in[2];

    const int E = in_sizes[2] / 4;
    const int N = in_sizes[0] / 10;
    const int* src = ei;
    const int* dst = ei + E;

    const float* p[4][6];   // w1, b1, w2, b2, root, bias
    for (int L = 0; L < 4; ++L)
        for (int j = 0; j < 6; ++j)
            p[L][j] = (const float*)d_in[3 + 6 * L + j];

    char* w = (char*)d_ws;
    auto carve = [&](size_t bytes) {
        char* q = w; w += (bytes + 255) & ~(size_t)255; return (void*)q;
    };
    _Float16* xin   = (_Float16*)carve((size_t)N * 8 * 2);
    _Float16* aggA  = (_Float16*)carve((size_t)N * 32 * 2);
    _Float16* aggB  = (_Float16*)carve((size_t)N * 32 * 2);
    _Float16* msg   = (_Float16*)carve((size_t)E * 32 * 2);
    float*    eaP   = (float*)carve((size_t)E * 4 * 4);
    int*      srcP  = (int*)carve((size_t)E * 4);
    int*      rowptr= (int*)carve((size_t)(N + 1) * 4);
    int*      cnt   = (int*)carve((size_t)N * 4);
    int*      bsum  = (int*)carve(4096);
    _Float16* bswz  = (_Float16*)carve((size_t)BSWZ_TOT * 2);
    float* out = (float*)d_out;

    Prm prm{};
    prm.x = x;
    for (int L = 0; L < 4; ++L) { prm.w2[L] = p[L][2]; prm.b2[L] = p[L][3]; }
    prm.xin = xin; prm.bswz = bswz; prm.cnt = cnt; prm.N = N;

    const int NB8 = (N * 8 + 255) / 256;
    const int NBC = (N + 255) / 256;                 // 391 (<=1024 for scan)
    const int EBK = (E + 255) / 256;

    const int ntileE = (E + 31) / 32;
    int NBE = (ntileE + 7) / 8;                      // 8 waves / block
    const int NBS32 = (N * 4 + 255) / 256;           // segsum OUT_C=32
    const int NBS2  = NBC;                           // segsum OUT_C=2

    // ---- CSR build (once) + prep: 5 dispatches ----
    prep      <<<430 + NB8 + NBC, 256, 0, stream>>>(prm, NB8, NBC);
    hist      <<<EBK, 256, 0, stream>>>(dst, cnt, E);
    scan_part <<<NBC, 256, 0, stream>>>(cnt, bsum, N);
    scan_final<<<NBC, 256, 0, stream>>>(cnt, bsum, rowptr, N);
    scatter   <<<EBK, 256, 0, stream>>>(src, dst, ea, cnt, srcP, eaP, E);

    // ---- layer 0 ----
    edge<8, 32><<<NBE, 512, 0, stream>>>(
        xin, nullptr, srcP, eaP, p[0][0], p[0][1], bswz + 0 * 512, msg, E, ntileE);
    segsum<6, 32><<<NBS32, 256, 0, stream>>>(
        xin, msg, rowptr, p[0][4], p[0][5], aggA, nullptr, N);

    // ---- layer 1 ----
    edge<32, 32><<<NBE, 512, 0, stream>>>(
        nullptr, aggA, srcP, eaP, p[1][0], p[1][1], bswz + 17 * 512, msg, E, ntileE);
    segsum<32, 32><<<NBS32, 256, 0, stream>>>(
        aggA, msg, rowptr, p[1][4], p[1][5], aggB, nullptr, N);

    // ---- layer 2 ----
    edge<32, 32><<<NBE, 512, 0, stream>>>(
        nullptr, aggB, srcP, eaP, p[2][0], p[2][1], bswz + 83 * 512, msg, E, ntileE);
    segsum<32, 32><<<NBS32, 256, 0, stream>>>(
        aggB, msg, rowptr, p[2][4], p[2][5], aggA, nullptr, N);

    // ---- layer 3 -> d_out ----
    edge<32, 2><<<NBE, 512, 0, stream>>>(
        nullptr, aggA, srcP, eaP, p[3][0], p[3][1], bswz + 149 * 512, msg, E, ntileE);
    segsum<32, 2><<<NBS2, 256, 0, stream>>>(
        aggA, msg, rowptr, p[3][4], p[3][5], nullptr, out, N);
}

// Round 13
// 131.846 us; speedup vs baseline: 1.3326x; 1.3326x over previous
//
#include <hip/hip_runtime.h>
#include <hip/hip_fp16.h>

typedef __attribute__((ext_vector_type(8)))  _Float16 half8v;  // 8 f16 = 4 VGPR
typedef __attribute__((ext_vector_type(16))) float    f32x16;

// bswz step layout (512 f16 per step), offsets in steps:
//  L0 real [0,17)   L0 self [17,19)
//  L1 real [19,85)  L1 self [85,88)
//  L2 real [88,154) L2 self [154,157)
//  L3 real [157,223) L3 self [223,226)
static constexpr int BSWZ_STEPS = 226;
static constexpr int BSWZ_TOT   = BSWZ_STEPS * 512;   // 115712 f16

struct Prm {
    const float* x;
    const float* w2[4]; const float* b2[4];
    const float* root[4]; const float* bias[4];
    _Float16* xin;    // N x 8 f16 (x[:,4:10], zero-padded)
    _Float16* bswz;
    _Float16* aggz;   // 3 * N * 32 f16 (agg0|agg1|agg2), zeroed here
    float* outz;      // N x 2 f32 (d_out), zeroed here
    int N;
};

// ---------------------------------------------------------------------------
// prep: [0,452) build bswz ; [452,452+NB8) pack xin ;
//       [.., +NZA) zero agg0..2 (uint4) ; [.., +NZO) zero out (float2).
// ---------------------------------------------------------------------------
__global__ __launch_bounds__(256) void prep(Prm p, int NB8, int NZA, int NZO)
{
    int b = blockIdx.x;
    if (b < 452) {                                   // ---- bswz ----
        int i = b * 256 + threadIdx.x;               // < 115712 exactly
        int T = i >> 9, t2 = i & 511;
        int j = t2 & 7, l = (t2 >> 3) & 63;
        int g = l >> 5, o = l & 31;
        int layer, cls, t;                           // cls: 0 real, 1 self
        if (T < 17)       { layer = 0; cls = 0; t = T; }
        else if (T < 19)  { layer = 0; cls = 1; t = T - 17; }
        else if (T < 85)  { layer = 1; cls = 0; t = T - 19; }
        else if (T < 88)  { layer = 1; cls = 1; t = T - 85; }
        else if (T < 154) { layer = 2; cls = 0; t = T - 88; }
        else if (T < 157) { layer = 2; cls = 1; t = T - 154; }
        else if (T < 223) { layer = 3; cls = 0; t = T - 157; }
        else              { layer = 3; cls = 1; t = T - 223; }
        const int INP   = (layer == 0) ? 8 : 32;
        const int IN_C  = (layer == 0) ? 6 : 32;
        const int OUT_C = (layer == 3) ? 2 : 32;
        float v = 0.f;
        if (cls == 0) {
            const int S_MAIN = 2 * INP;
            if (t < S_MAIN) {
                int kap = 16 * t + 8 * g + j;
                int k  = (INP == 8) ? (kap >> 3) : (kap >> 5);
                int ii = (INP == 8) ? (kap & 7)  : (kap & 31);
                if (ii < IN_C && o < OUT_C)
                    v = p.w2[layer][(size_t)k * (IN_C * OUT_C) + ii * OUT_C + o];
            } else {
                int ii = 16 * (t - S_MAIN) + 8 * g + j;
                if (ii < IN_C && o < OUT_C)
                    v = p.b2[layer][ii * OUT_C + o];
            }
        } else {
            const int nroot = (layer == 0) ? 1 : 2;
            if (t < nroot) {
                int ii = 16 * t + 8 * g + j;
                if (ii < IN_C && o < OUT_C)
                    v = p.root[layer][ii * OUT_C + o];
            } else {
                if (g == 0 && j == 0 && o < OUT_C)
                    v = p.bias[layer][o];
            }
        }
        p.bswz[i] = (_Float16)v;
    } else if (b < 452 + NB8) {                      // ---- pack xin ----
        int i = (b - 452) * 256 + threadIdx.x;
        if (i < p.N * 8) {
            int v = i >> 3, c = i & 7;
            float val = (c < 6) ? p.x[(size_t)v * 10 + 4 + c] : 0.f;
            p.xin[i] = (_Float16)val;
        }
    } else if (b < 452 + NB8 + NZA) {                // ---- zero agg0..2 ----
        long long i = (long long)(b - 452 - NB8) * 256 + threadIdx.x;
        if (i < (long long)p.N * 12)                 // 3*N*32*2B / 16B
            ((uint4*)p.aggz)[i] = uint4{0u, 0u, 0u, 0u};
    } else {                                         // ---- zero out ----
        int v = (b - 452 - NB8 - NZA) * 256 + threadIdx.x;
        if (v < p.N)
            ((float2*)p.outz)[v] = float2{0.f, 0.f};
    }
}

// gather 32 f16 feats for node s, relu in packed f16
static __device__ __forceinline__ void gather32h(
    const _Float16* __restrict__ fprev, int s, int g, half8v& xh0, half8v& xh1)
{
    const half8v* fp = (const half8v*)(fprev + (size_t)s * 32);
    xh0 = fp[g];
    xh1 = fp[2 + g];
    #pragma unroll
    for (int j = 0; j < 8; ++j) {
        xh0[j] = xh0[j] > (_Float16)0.f ? xh0[j] : (_Float16)0.f;
        xh1[j] = xh1[j] > (_Float16)0.f ? xh1[j] : (_Float16)0.f;
    }
}

// paired pk-f16 atomic: lanes o and o^1 hold the same row, cols o / o^1.
// Even lane packs (mine, other) and issues ONE global_atomic_pk_add_f16.
static __device__ __forceinline__ void pk_atomic_row(
    _Float16* __restrict__ aggH, int row, int o, float mine)
{
    float oth = __shfl_xor(mine, 1);
    if ((o & 1) == 0 && row >= 0) {
        __half2 v = __floats2half2_rn(mine, oth);
        unsafeAtomicAdd((__half2*)aggH + (((size_t)row << 5) + o) / 2, v);
    }
}

// ---------------------------------------------------------------------------
// Edge kernel, LDS-staged B, pk-f16 atomics, TWO edge-tiles per wave:
// each B fragment is read from LDS once and feeds 4 MFMAs (2 per tile) —
// halves the ds_read_b128 term (the R12-identified per-CU bottleneck) and
// doubles gather ILP.  N-tiles (node term, 2-3 MFMAs) processed singly.
// C layout: col = lane&31 = o, row = (r&3)+8*(r>>2)+4*(lane>>5).
// ---------------------------------------------------------------------------
template<int INP, int OUT_C>
__global__ __launch_bounds__(512, 4) void edge(
    const _Float16* __restrict__ xin,     // layer0 features (N x 8)
    const _Float16* __restrict__ fprev,   // mid features (N x 32 f16, pre-relu)
    const int*      __restrict__ src,
    const int*      __restrict__ dst,
    const float*    __restrict__ ea,
    const float*    __restrict__ w1,      // (4,32) row-major
    const float*    __restrict__ b1,      // (32)
    const _Float16* __restrict__ bAll,    // real || self fragments, contiguous
    _Float16* __restrict__ aggH,          // N x 32 f16 (OUT_C==32)
    float*    __restrict__ aggF,          // N x 2 f32  (OUT_C==2)
    int E, int N, int npairE, int ntileE, int nwork)
{
    constexpr int NREAL = (INP == 32) ? 66 : 17;
    constexpr int NSELF = (INP == 32) ? 3  : 2;
    constexpr int NSTEP = NREAL + NSELF;

    __shared__ half8v ldsb[NSTEP * 64];
    {
        const half8v* bp = (const half8v*)bAll;
        for (int i = threadIdx.x; i < NSTEP * 64; i += 512)
            ldsb[i] = bp[i];
    }
    __syncthreads();

    const int lane = threadIdx.x & 63;
    const int g = lane >> 5, o = lane & 31;
    const int lrow = lane & 31;
    const int wv = (blockIdx.x * 512 + threadIdx.x) >> 6;
    const int nw = gridDim.x * 8;

    half8v ones;
    #pragma unroll
    for (int j = 0; j < 8; ++j) ones[j] = (_Float16)0.f;
    ones[0] = (_Float16)1.f;

    // epilogue for one E-tile
    auto epiE = [&](int e0, const f32x16& C) {
        if constexpr (OUT_C == 32) {
            #pragma unroll
            for (int q = 0; q < 4; ++q) {
                const int eb = e0 + 8 * q + 4 * g;
                int rows[4];
                if (eb + 3 < E) {
                    const int4 dd = *(const int4*)(dst + eb);
                    rows[0] = dd.x; rows[1] = dd.y; rows[2] = dd.z; rows[3] = dd.w;
                } else {
                    #pragma unroll
                    for (int m = 0; m < 4; ++m)
                        rows[m] = (eb + m < E) ? dst[eb + m] : -1;
                }
                #pragma unroll
                for (int m = 0; m < 4; ++m)
                    pk_atomic_row(aggH, rows[m], o, C[4*q + m]);
            }
        } else {
            if (o < OUT_C) {
                #pragma unroll
                for (int q = 0; q < 4; ++q) {
                    const int eb = e0 + 8 * q + 4 * g;
                    #pragma unroll
                    for (int m = 0; m < 4; ++m)
                        if (eb + m < E)
                            unsafeAtomicAdd(aggF + (size_t)dst[eb + m] * OUT_C + o,
                                            C[4*q + m]);
                }
            }
        }
    };

    for (int wk = wv; wk < nwork; wk += nw) {
        if (wk < npairE) {
            // ============ pair of real-edge tiles ============
            const int t0 = 2 * wk, t1 = 2 * wk + 1;
            const bool has1 = (t1 < ntileE);
            const int e0a = t0 * 32, e0b = t1 * 32;
            const int eca = (e0a + lrow < E) ? e0a + lrow : E - 1;
            const int ecb = has1 ? ((e0b + lrow < E) ? e0b + lrow : E - 1) : eca;
            const int sa = src[eca], sb = src[ecb];
            const float4 avA = *(const float4*)(ea + 4ll * eca);
            const float4 avB = *(const float4*)(ea + 4ll * ecb);

            half8v xa0, xa1, xb0, xb1;
            if constexpr (INP == 32) {
                gather32h(fprev, sa, g, xa0, xa1);
                gather32h(fprev, sb, g, xb0, xb1);
            } else {
                xa0 = *(const half8v*)(xin + (size_t)sa * 8);
                xb0 = *(const half8v*)(xin + (size_t)sb * 8);
            }

            f32x16 CA, CB;
            #pragma unroll
            for (int i = 0; i < 16; ++i) { CA[i] = 0.f; CB[i] = 0.f; }

            if constexpr (INP == 32) {
                #pragma unroll 4
                for (int k = 0; k < 32; ++k) {
                    half8v bf0 = ldsb[(2*k    ) * 64 + lane];
                    half8v bf1 = ldsb[(2*k + 1) * 64 + lane];
                    float hka = fmaf(avA.x, w1[k], b1[k]);
                    hka = fmaf(avA.y, w1[32 + k], hka);
                    hka = fmaf(avA.z, w1[64 + k], hka);
                    hka = fmaf(avA.w, w1[96 + k], hka);
                    hka = fmaxf(hka, 0.f);
                    float hkb = fmaf(avB.x, w1[k], b1[k]);
                    hkb = fmaf(avB.y, w1[32 + k], hkb);
                    hkb = fmaf(avB.z, w1[64 + k], hkb);
                    hkb = fmaf(avB.w, w1[96 + k], hkb);
                    hkb = fmaxf(hkb, 0.f);
                    const _Float16 ha = (_Float16)hka, hb = (_Float16)hkb;
                    half8v hsa, hsb;
                    #pragma unroll
                    for (int j = 0; j < 8; ++j) { hsa[j] = ha; hsb[j] = hb; }
                    CA = __builtin_amdgcn_mfma_f32_32x32x16_f16(hsa * xa0, bf0, CA, 0, 0, 0);
                    CA = __builtin_amdgcn_mfma_f32_32x32x16_f16(hsa * xa1, bf1, CA, 0, 0, 0);
                    CB = __builtin_amdgcn_mfma_f32_32x32x16_f16(hsb * xb0, bf0, CB, 0, 0, 0);
                    CB = __builtin_amdgcn_mfma_f32_32x32x16_f16(hsb * xb1, bf1, CB, 0, 0, 0);
                }
                {   // b2 tail, h == 1
                    half8v bf0 = ldsb[64 * 64 + lane];
                    half8v bf1 = ldsb[65 * 64 + lane];
                    CA = __builtin_amdgcn_mfma_f32_32x32x16_f16(xa0, bf0, CA, 0, 0, 0);
                    CA = __builtin_amdgcn_mfma_f32_32x32x16_f16(xa1, bf1, CA, 0, 0, 0);
                    CB = __builtin_amdgcn_mfma_f32_32x32x16_f16(xb0, bf0, CB, 0, 0, 0);
                    CB = __builtin_amdgcn_mfma_f32_32x32x16_f16(xb1, bf1, CB, 0, 0, 0);
                }
            } else {
                #pragma unroll 4
                for (int t = 0; t < 16; ++t) {
                    half8v bf = ldsb[t * 64 + lane];
                    const int k = 2 * t + g;          // lane-dependent
                    float hka = fmaf(avA.x, w1[k], b1[k]);
                    hka = fmaf(avA.y, w1[32 + k], hka);
                    hka = fmaf(avA.z, w1[64 + k], hka);
                    hka = fmaf(avA.w, w1[96 + k], hka);
                    hka = fmaxf(hka, 0.f);
                    float hkb = fmaf(avB.x, w1[k], b1[k]);
                    hkb = fmaf(avB.y, w1[32 + k], hkb);
                    hkb = fmaf(avB.z, w1[64 + k], hkb);
                    hkb = fmaf(avB.w, w1[96 + k], hkb);
                    hkb = fmaxf(hkb, 0.f);
                    const _Float16 ha = (_Float16)hka, hb = (_Float16)hkb;
                    half8v hsa, hsb;
                    #pragma unroll
                    for (int j = 0; j < 8; ++j) { hsa[j] = ha; hsb[j] = hb; }
                    CA = __builtin_amdgcn_mfma_f32_32x32x16_f16(hsa * xa0, bf, CA, 0, 0, 0);
                    CB = __builtin_amdgcn_mfma_f32_32x32x16_f16(hsb * xb0, bf, CB, 0, 0, 0);
                }
                {   // b2 tail
                    half8v bf = ldsb[16 * 64 + lane];
                    half8v zz;
                    #pragma unroll
                    for (int j = 0; j < 8; ++j) zz[j] = (_Float16)0.f;
                    half8v aA = (g == 0) ? xa0 : zz;
                    half8v aB = (g == 0) ? xb0 : zz;
                    CA = __builtin_amdgcn_mfma_f32_32x32x16_f16(aA, bf, CA, 0, 0, 0);
                    CB = __builtin_amdgcn_mfma_f32_32x32x16_f16(aB, bf, CB, 0, 0, 0);
                }
            }

            epiE(e0a, CA);
            if (has1) epiE(e0b, CB);
        } else {
            // ============ self tile (node term) ============
            const int v0 = (wk - npairE) * 32;
            const int vr = v0 + lrow;
            const int vc = vr < N ? vr : (N - 1);

            f32x16 C;
            #pragma unroll
            for (int i = 0; i < 16; ++i) C[i] = 0.f;

            if constexpr (INP == 32) {
                half8v xh0, xh1;
                gather32h(fprev, vc, g, xh0, xh1);
                C = __builtin_amdgcn_mfma_f32_32x32x16_f16(xh0,  ldsb[(NREAL+0)*64 + lane], C, 0, 0, 0);
                C = __builtin_amdgcn_mfma_f32_32x32x16_f16(xh1,  ldsb[(NREAL+1)*64 + lane], C, 0, 0, 0);
                C = __builtin_amdgcn_mfma_f32_32x32x16_f16(ones, ldsb[(NREAL+2)*64 + lane], C, 0, 0, 0);
            } else {
                half8v xh0 = *(const half8v*)(xin + (size_t)vc * 8);
                C = __builtin_amdgcn_mfma_f32_32x32x16_f16(xh0,  ldsb[(NREAL+0)*64 + lane], C, 0, 0, 0);
                C = __builtin_amdgcn_mfma_f32_32x32x16_f16(ones, ldsb[(NREAL+1)*64 + lane], C, 0, 0, 0);
            }

            if constexpr (OUT_C == 32) {
                #pragma unroll
                for (int q = 0; q < 4; ++q) {
                    #pragma unroll
                    for (int m = 0; m < 4; ++m) {
                        const int row = v0 + 8*q + 4*g + m;
                        pk_atomic_row(aggH, row < N ? row : -1, o, C[4*q + m]);
                    }
                }
            } else {
                if (o < OUT_C) {
                    #pragma unroll
                    for (int q = 0; q < 4; ++q) {
                        #pragma unroll
                        for (int m = 0; m < 4; ++m) {
                            const int row = v0 + 8*q + 4*g + m;
                            if (row < N)
                                unsafeAtomicAdd(aggF + (size_t)row * OUT_C + o, C[4*q + m]);
                        }
                    }
                }
            }
        }
    }
}

// ---------------------------------------------------------------------------
extern "C" void kernel_launch(void* const* d_in, const int* in_sizes, int n_in,
                              void* d_out, int out_size, void* d_ws, size_t ws_size,
                              hipStream_t stream)
{
    const float* x  = (const float*)d_in[0];
    const int*   ei = (const int*)d_in[1];
    const float* ea = (const float*)d_in[2];

    const int E = in_sizes[2] / 4;
    const int N = in_sizes[0] / 10;
    const int* src = ei;
    const int* dst = ei + E;

    const float* p[4][6];   // w1, b1, w2, b2, root, bias
    for (int L = 0; L < 4; ++L)
        for (int j = 0; j < 6; ++j)
            p[L][j] = (const float*)d_in[3 + 6 * L + j];

    char* w = (char*)d_ws;
    auto carve = [&](size_t bytes) {
        char* q = w; w += (bytes + 255) & ~(size_t)255; return (void*)q;
    };
    _Float16* xin  = (_Float16*)carve((size_t)N * 8 * 2);
    _Float16* aggz = (_Float16*)carve((size_t)3 * N * 32 * 2); // agg0|agg1|agg2 f16
    _Float16* bswz = (_Float16*)carve((size_t)BSWZ_TOT * 2);
    _Float16* agg0 = aggz;
    _Float16* agg1 = aggz + (size_t)N * 32;
    _Float16* agg2 = aggz + (size_t)2 * N * 32;
    float* out  = (float*)d_out;

    Prm prm{};
    prm.x = x;
    for (int L = 0; L < 4; ++L) {
        prm.w2[L] = p[L][2]; prm.b2[L] = p[L][3];
        prm.root[L] = p[L][4]; prm.bias[L] = p[L][5];
    }
    prm.xin = xin; prm.bswz = bswz; prm.aggz = aggz; prm.outz = out; prm.N = N;

    const int NB8 = (N * 8 + 255) / 256;
    const int NZA = (N * 12 + 255) / 256;            // 3*N*32*2B / 16B uint4
    const int NZO = (N + 255) / 256;                 // N float2

    const int ntileE = (E + 31) / 32;
    const int ntileN = (N + 31) / 32;
    const int npairE = (ntileE + 1) / 2;
    const int nwork  = npairE + ntileN;
    int NB = (nwork + 7) / 8;                        // 8 waves / block
    if (NB > 512) NB = 512;                          // 2 blocks/CU co-resident

    // 5 dispatches total
    prep<<<452 + NB8 + NZA + NZO, 256, 0, stream>>>(prm, NB8, NZA, NZO);

    edge<8, 32><<<NB, 512, 0, stream>>>(             // layer 0
        xin, nullptr, src, dst, ea, p[0][0], p[0][1],
        bswz + 0 * 512, agg0, nullptr, E, N, npairE, ntileE, nwork);

    edge<32, 32><<<NB, 512, 0, stream>>>(            // layer 1
        nullptr, agg0, src, dst, ea, p[1][0], p[1][1],
        bswz + 19 * 512, agg1, nullptr, E, N, npairE, ntileE, nwork);

    edge<32, 32><<<NB, 512, 0, stream>>>(            // layer 2
        nullptr, agg1, src, dst, ea, p[2][0], p[2][1],
        bswz + 88 * 512, agg2, nullptr, E, N, npairE, ntileE, nwork);

    edge<32, 2><<<NB, 512, 0, stream>>>(             // layer 3 -> d_out
        nullptr, agg2, src, dst, ea, p[3][0], p[3][1],
        bswz + 157 * 512, nullptr, out, E, N, npairE, ntileE, nwork);
}

// Round 14
// 120.478 us; speedup vs baseline: 1.4584x; 1.0944x over previous
//
#include <hip/hip_runtime.h>
#include <hip/hip_fp16.h>

typedef __attribute__((ext_vector_type(8)))  _Float16 half8v;  // 8 f16 = 4 VGPR
typedef __attribute__((ext_vector_type(16))) float    f32x16;

// bswz step layout (512 f16 per step), offsets in steps:
//  L0 real [0,17)   L0 self [17,19)
//  L1 real [19,85)  L1 self [85,88)
//  L2 real [88,154) L2 self [154,157)
//  L3 real [157,223) L3 self [223,226)
static constexpr int BSWZ_STEPS = 226;
static constexpr int BSWZ_TOT   = BSWZ_STEPS * 512;   // 115712 f16

struct Prm {
    const float* x;
    const float* w2[4]; const float* b2[4];
    const float* root[4]; const float* bias[4];
    _Float16* xin;    // N x 8 f16 (x[:,4:10], zero-padded)
    _Float16* bswz;
    _Float16* aggz;   // 3 * N * 32 f16 (agg0|agg1|agg2), zeroed here
    float* outz;      // N x 2 f32 (d_out), zeroed here
    int N;
};

// ---------------------------------------------------------------------------
// prep: [0,452) build bswz ; [452,452+NB8) pack xin ;
//       [.., +NZA) zero agg0..2 (uint4) ; [.., +NZO) zero out (float2).
// ---------------------------------------------------------------------------
__global__ __launch_bounds__(256) void prep(Prm p, int NB8, int NZA, int NZO)
{
    int b = blockIdx.x;
    if (b < 452) {                                   // ---- bswz ----
        int i = b * 256 + threadIdx.x;               // < 115712 exactly
        int T = i >> 9, t2 = i & 511;
        int j = t2 & 7, l = (t2 >> 3) & 63;
        int g = l >> 5, o = l & 31;
        int layer, cls, t;                           // cls: 0 real, 1 self
        if (T < 17)       { layer = 0; cls = 0; t = T; }
        else if (T < 19)  { layer = 0; cls = 1; t = T - 17; }
        else if (T < 85)  { layer = 1; cls = 0; t = T - 19; }
        else if (T < 88)  { layer = 1; cls = 1; t = T - 85; }
        else if (T < 154) { layer = 2; cls = 0; t = T - 88; }
        else if (T < 157) { layer = 2; cls = 1; t = T - 154; }
        else if (T < 223) { layer = 3; cls = 0; t = T - 157; }
        else              { layer = 3; cls = 1; t = T - 223; }
        const int INP   = (layer == 0) ? 8 : 32;
        const int IN_C  = (layer == 0) ? 6 : 32;
        const int OUT_C = (layer == 3) ? 2 : 32;
        float v = 0.f;
        if (cls == 0) {
            const int S_MAIN = 2 * INP;
            if (t < S_MAIN) {
                int kap = 16 * t + 8 * g + j;
                int k  = (INP == 8) ? (kap >> 3) : (kap >> 5);
                int ii = (INP == 8) ? (kap & 7)  : (kap & 31);
                if (ii < IN_C && o < OUT_C)
                    v = p.w2[layer][(size_t)k * (IN_C * OUT_C) + ii * OUT_C + o];
            } else {
                int ii = 16 * (t - S_MAIN) + 8 * g + j;
                if (ii < IN_C && o < OUT_C)
                    v = p.b2[layer][ii * OUT_C + o];
            }
        } else {
            const int nroot = (layer == 0) ? 1 : 2;
            if (t < nroot) {
                int ii = 16 * t + 8 * g + j;
                if (ii < IN_C && o < OUT_C)
                    v = p.root[layer][ii * OUT_C + o];
            } else {
                if (g == 0 && j == 0 && o < OUT_C)
                    v = p.bias[layer][o];
            }
        }
        p.bswz[i] = (_Float16)v;
    } else if (b < 452 + NB8) {                      // ---- pack xin ----
        int i = (b - 452) * 256 + threadIdx.x;
        if (i < p.N * 8) {
            int v = i >> 3, c = i & 7;
            float val = (c < 6) ? p.x[(size_t)v * 10 + 4 + c] : 0.f;
            p.xin[i] = (_Float16)val;
        }
    } else if (b < 452 + NB8 + NZA) {                // ---- zero agg0..2 ----
        long long i = (long long)(b - 452 - NB8) * 256 + threadIdx.x;
        if (i < (long long)p.N * 12)                 // 3*N*32*2B / 16B
            ((uint4*)p.aggz)[i] = uint4{0u, 0u, 0u, 0u};
    } else {                                         // ---- zero out ----
        int v = (b - 452 - NB8 - NZA) * 256 + threadIdx.x;
        if (v < p.N)
            ((float2*)p.outz)[v] = float2{0.f, 0.f};
    }
}

// gather 32 f16 feats for node s, relu in packed f16
static __device__ __forceinline__ void gather32h(
    const _Float16* __restrict__ fprev, int s, int g, half8v& xh0, half8v& xh1)
{
    const half8v* fp = (const half8v*)(fprev + (size_t)s * 32);
    xh0 = fp[g];
    xh1 = fp[2 + g];
    #pragma unroll
    for (int j = 0; j < 8; ++j) {
        xh0[j] = xh0[j] > (_Float16)0.f ? xh0[j] : (_Float16)0.f;
        xh1[j] = xh1[j] > (_Float16)0.f ? xh1[j] : (_Float16)0.f;
    }
}

// paired pk-f16 atomic: lanes o and o^1 hold the same row, cols o / o^1.
// Even lane packs (mine, other) and issues ONE global_atomic_pk_add_f16.
static __device__ __forceinline__ void pk_atomic_row(
    _Float16* __restrict__ aggH, int row, int o, float mine)
{
    float oth = __shfl_xor(mine, 1);
    if ((o & 1) == 0 && row >= 0) {
        __half2 v = __floats2half2_rn(mine, oth);
        unsafeAtomicAdd((__half2*)aggH + (((size_t)row << 5) + o) / 2, v);
    }
}

// ---------------------------------------------------------------------------
// Edge kernel (R11 structure), 1024-thread blocks for 32 waves/CU:
// 2 blocks/CU x 69KB LDS = 138KB <= 160KB, 2048 threads = CU capacity.
// LDS-staged B fragments; pk-f16 atomic aggregation.
//  tiles [0, ntileE):    32 real edges — MFMA over K = 32*INP + b2 tail
//  tiles [ntileE, ntot): 32 nodes     — 2-3 MFMAs (root term + bias)
// C layout: col = lane&31 = o, row = (r&3)+8*(r>>2)+4*(lane>>5).
// ---------------------------------------------------------------------------
template<int INP, int OUT_C>
__global__ __launch_bounds__(1024, 8) void edge(
    const _Float16* __restrict__ xin,     // layer0 features (N x 8)
    const _Float16* __restrict__ fprev,   // mid features (N x 32 f16, pre-relu)
    const int*      __restrict__ src,
    const int*      __restrict__ dst,
    const float*    __restrict__ ea,
    const float*    __restrict__ w1,      // (4,32) row-major
    const float*    __restrict__ b1,      // (32)
    const _Float16* __restrict__ bAll,    // real || self fragments, contiguous
    _Float16* __restrict__ aggH,          // N x 32 f16 (OUT_C==32)
    float*    __restrict__ aggF,          // N x 2 f32  (OUT_C==2)
    int E, int N, int ntileE, int ntot)
{
    constexpr int NREAL = (INP == 32) ? 66 : 17;
    constexpr int NSELF = (INP == 32) ? 3  : 2;
    constexpr int NSTEP = NREAL + NSELF;

    __shared__ half8v ldsb[NSTEP * 64];
    {
        const half8v* bp = (const half8v*)bAll;
        for (int i = threadIdx.x; i < NSTEP * 64; i += 1024)
            ldsb[i] = bp[i];
    }
    __syncthreads();

    const int lane = threadIdx.x & 63;
    const int g = lane >> 5, o = lane & 31;
    const int lrow = lane & 31;
    const int wv = (blockIdx.x * 1024 + threadIdx.x) >> 6;
    const int nw = gridDim.x * 16;

    half8v ones;
    #pragma unroll
    for (int j = 0; j < 8; ++j) ones[j] = (_Float16)0.f;
    ones[0] = (_Float16)1.f;

    for (int tile = wv; tile < ntot; tile += nw) {
        f32x16 C;
        #pragma unroll
        for (int i = 0; i < 16; ++i) C[i] = 0.f;

        if (tile < ntileE) {
            // ================= real edges =================
            const int e0 = tile * 32;
            const int er = e0 + lrow;
            const int ec = er < E ? er : (E - 1);
            const int s  = src[ec];
            const float4 av = *(const float4*)(ea + 4ll * ec);

            half8v xh0, xh1;
            if constexpr (INP == 32) gather32h(fprev, s, g, xh0, xh1);
            else                     xh0 = *(const half8v*)(xin + (size_t)s * 8);

            if constexpr (INP == 32) {
                #pragma unroll 4
                for (int k = 0; k < 32; ++k) {
                    half8v bf0 = ldsb[(2*k    ) * 64 + lane];
                    half8v bf1 = ldsb[(2*k + 1) * 64 + lane];
                    float hk = fmaf(av.x, w1[k], b1[k]);
                    hk = fmaf(av.y, w1[32 + k], hk);
                    hk = fmaf(av.z, w1[64 + k], hk);
                    hk = fmaf(av.w, w1[96 + k], hk);
                    hk = fmaxf(hk, 0.f);
                    const _Float16 hh = (_Float16)hk;
                    half8v hs;
                    #pragma unroll
                    for (int j = 0; j < 8; ++j) hs[j] = hh;
                    C = __builtin_amdgcn_mfma_f32_32x32x16_f16(hs * xh0, bf0, C, 0, 0, 0);
                    C = __builtin_amdgcn_mfma_f32_32x32x16_f16(hs * xh1, bf1, C, 0, 0, 0);
                }
                C = __builtin_amdgcn_mfma_f32_32x32x16_f16(xh0, ldsb[64*64 + lane], C, 0, 0, 0);
                C = __builtin_amdgcn_mfma_f32_32x32x16_f16(xh1, ldsb[65*64 + lane], C, 0, 0, 0);
            } else {
                #pragma unroll 4
                for (int t = 0; t < 16; ++t) {
                    half8v bf = ldsb[t * 64 + lane];
                    const int k = 2 * t + g;              // lane-dependent
                    float hk = fmaf(av.x, w1[k], b1[k]);
                    hk = fmaf(av.y, w1[32 + k], hk);
                    hk = fmaf(av.z, w1[64 + k], hk);
                    hk = fmaf(av.w, w1[96 + k], hk);
                    hk = fmaxf(hk, 0.f);
                    const _Float16 hh = (_Float16)hk;
                    half8v hs;
                    #pragma unroll
                    for (int j = 0; j < 8; ++j) hs[j] = hh;
                    C = __builtin_amdgcn_mfma_f32_32x32x16_f16(hs * xh0, bf, C, 0, 0, 0);
                }
                half8v zz;
                #pragma unroll
                for (int j = 0; j < 8; ++j) zz[j] = (_Float16)0.f;
                half8v a = (g == 0) ? xh0 : zz;           // b2 tail
                C = __builtin_amdgcn_mfma_f32_32x32x16_f16(a, ldsb[16*64 + lane], C, 0, 0, 0);
            }

            // epilogue: reg 4q+m -> edge row e0+8q+4g+m, col o
            if constexpr (OUT_C == 32) {
                #pragma unroll
                for (int q = 0; q < 4; ++q) {
                    const int eb = e0 + 8 * q + 4 * g;
                    int rows[4];
                    if (eb + 3 < E) {
                        const int4 dd = *(const int4*)(dst + eb);
                        rows[0] = dd.x; rows[1] = dd.y; rows[2] = dd.z; rows[3] = dd.w;
                    } else {
                        #pragma unroll
                        for (int m = 0; m < 4; ++m)
                            rows[m] = (eb + m < E) ? dst[eb + m] : -1;
                    }
                    #pragma unroll
                    for (int m = 0; m < 4; ++m)
                        pk_atomic_row(aggH, rows[m], o, C[4*q + m]);
                }
            } else {
                if (o < OUT_C) {
                    #pragma unroll
                    for (int q = 0; q < 4; ++q) {
                        const int eb = e0 + 8 * q + 4 * g;
                        #pragma unroll
                        for (int m = 0; m < 4; ++m)
                            if (eb + m < E)
                                unsafeAtomicAdd(aggF + (size_t)dst[eb + m] * OUT_C + o,
                                                C[4*q + m]);
                    }
                }
            }
        } else {
            // ================= self edges (node term) =================
            const int v0 = (tile - ntileE) * 32;
            const int vr = v0 + lrow;
            const int vc = vr < N ? vr : (N - 1);

            if constexpr (INP == 32) {
                half8v xh0, xh1;
                gather32h(fprev, vc, g, xh0, xh1);
                C = __builtin_amdgcn_mfma_f32_32x32x16_f16(xh0,  ldsb[(NREAL+0)*64 + lane], C, 0, 0, 0);
                C = __builtin_amdgcn_mfma_f32_32x32x16_f16(xh1,  ldsb[(NREAL+1)*64 + lane], C, 0, 0, 0);
                C = __builtin_amdgcn_mfma_f32_32x32x16_f16(ones, ldsb[(NREAL+2)*64 + lane], C, 0, 0, 0);
            } else {
                half8v xh0 = *(const half8v*)(xin + (size_t)vc * 8);
                C = __builtin_amdgcn_mfma_f32_32x32x16_f16(xh0,  ldsb[(NREAL+0)*64 + lane], C, 0, 0, 0);
                C = __builtin_amdgcn_mfma_f32_32x32x16_f16(ones, ldsb[(NREAL+1)*64 + lane], C, 0, 0, 0);
            }

            if constexpr (OUT_C == 32) {
                #pragma unroll
                for (int q = 0; q < 4; ++q) {
                    #pragma unroll
                    for (int m = 0; m < 4; ++m) {
                        const int row = v0 + 8*q + 4*g + m;
                        pk_atomic_row(aggH, row < N ? row : -1, o, C[4*q + m]);
                    }
                }
            } else {
                if (o < OUT_C) {
                    #pragma unroll
                    for (int q = 0; q < 4; ++q) {
                        #pragma unroll
                        for (int m = 0; m < 4; ++m) {
                            const int row = v0 + 8*q + 4*g + m;
                            if (row < N)
                                unsafeAtomicAdd(aggF + (size_t)row * OUT_C + o, C[4*q + m]);
                        }
                    }
                }
            }
        }
    }
}

// ---------------------------------------------------------------------------
extern "C" void kernel_launch(void* const* d_in, const int* in_sizes, int n_in,
                              void* d_out, int out_size, void* d_ws, size_t ws_size,
                              hipStream_t stream)
{
    const float* x  = (const float*)d_in[0];
    const int*   ei = (const int*)d_in[1];
    const float* ea = (const float*)d_in[2];

    const int E = in_sizes[2] / 4;
    const int N = in_sizes[0] / 10;
    const int* src = ei;
    const int* dst = ei + E;

    const float* p[4][6];   // w1, b1, w2, b2, root, bias
    for (int L = 0; L < 4; ++L)
        for (int j = 0; j < 6; ++j)
            p[L][j] = (const float*)d_in[3 + 6 * L + j];

    char* w = (char*)d_ws;
    auto carve = [&](size_t bytes) {
        char* q = w; w += (bytes + 255) & ~(size_t)255; return (void*)q;
    };
    _Float16* xin  = (_Float16*)carve((size_t)N * 8 * 2);
    _Float16* aggz = (_Float16*)carve((size_t)3 * N * 32 * 2); // agg0|agg1|agg2 f16
    _Float16* bswz = (_Float16*)carve((size_t)BSWZ_TOT * 2);
    _Float16* agg0 = aggz;
    _Float16* agg1 = aggz + (size_t)N * 32;
    _Float16* agg2 = aggz + (size_t)2 * N * 32;
    float* out  = (float*)d_out;

    Prm prm{};
    prm.x = x;
    for (int L = 0; L < 4; ++L) {
        prm.w2[L] = p[L][2]; prm.b2[L] = p[L][3];
        prm.root[L] = p[L][4]; prm.bias[L] = p[L][5];
    }
    prm.xin = xin; prm.bswz = bswz; prm.aggz = aggz; prm.outz = out; prm.N = N;

    const int NB8 = (N * 8 + 255) / 256;
    const int NZA = (N * 12 + 255) / 256;            // 3*N*32*2B / 16B uint4
    const int NZO = (N + 255) / 256;                 // N float2

    const int ntileE = (E + 31) / 32;
    const int ntileN = (N + 31) / 32;
    const int ntot   = ntileE + ntileN;
    int NB = (ntot + 15) / 16;                       // 16 waves / block
    if (NB > 512) NB = 512;                          // 2 blocks/CU co-resident

    // 5 dispatches total
    prep<<<452 + NB8 + NZA + NZO, 256, 0, stream>>>(prm, NB8, NZA, NZO);

    edge<8, 32><<<NB, 1024, 0, stream>>>(            // layer 0
        xin, nullptr, src, dst, ea, p[0][0], p[0][1],
        bswz + 0 * 512, agg0, nullptr, E, N, ntileE, ntot);

    edge<32, 32><<<NB, 1024, 0, stream>>>(           // layer 1
        nullptr, agg0, src, dst, ea, p[1][0], p[1][1],
        bswz + 19 * 512, agg1, nullptr, E, N, ntileE, ntot);

    edge<32, 32><<<NB, 1024, 0, stream>>>(           // layer 2
        nullptr, agg1, src, dst, ea, p[2][0], p[2][1],
        bswz + 88 * 512, agg2, nullptr, E, N, ntileE, ntot);

    edge<32, 2><<<NB, 1024, 0, stream>>>(            // layer 3 -> d_out
        nullptr, agg2, src, dst, ea, p[3][0], p[3][1],
        bswz + 157 * 512, nullptr, out, E, N, ntileE, ntot);
}

// Round 17
// 112.270 us; speedup vs baseline: 1.5650x; 1.0731x over previous
//
#include <hip/hip_runtime.h>
#include <hip/hip_fp16.h>

typedef __attribute__((ext_vector_type(2)))  _Float16 half2v;  // 2 f16 = 1 VGPR
typedef __attribute__((ext_vector_type(8)))  _Float16 half8v;  // 8 f16 = 4 VGPR
typedef __attribute__((ext_vector_type(16))) float    f32x16;

// bswz step layout (512 f16 per step), offsets in steps:
//  L0 real [0,17)   L0 self [17,19)
//  L1 real [19,85)  L1 self [85,88)
//  L2 real [88,154) L2 self [154,157)
//  L3 real [157,223) L3 self [223,226)
// then 4 x 160 f16 of packed w1h/b1h per layer.
static constexpr int BSWZ_STEPS = 226;
static constexpr int BSWZ_TOT   = BSWZ_STEPS * 512;   // 115712 f16
static constexpr int W1H_TOT    = 4 * 160;            // w1h[4][32] + b1h[32] per layer

struct Prm {
    const float* x;
    const float* w1[4]; const float* b1[4];
    const float* w2[4]; const float* b2[4];
    const float* root[4]; const float* bias[4];
    _Float16* xin;    // N x 8 f16 (x[:,4:10], zero-padded)
    _Float16* bswz;
    _Float16* w1h;    // 640 f16: per layer {w1 k-pairs (4x16 half2), b1 (16 half2)}
    _Float16* aggz;   // 3 * N * 32 f16 (agg0|agg1|agg2), zeroed here
    float* outz;      // N x 2 f32 (d_out), zeroed here
    int N;
};

// ---------------------------------------------------------------------------
// prep: [0,452) build bswz ; [452,452+NB8) pack xin ;
//       [.., +NZA) zero agg0..2 ; [.., +NZO) zero out ; last block: w1h/b1h
//       (grid-stride over all 640 elements — R16 bug: only 0..255 written).
// ---------------------------------------------------------------------------
__global__ __launch_bounds__(256) void prep(Prm p, int NB8, int NZA, int NZO)
{
    int b = blockIdx.x;
    if (b < 452) {                                   // ---- bswz ----
        int i = b * 256 + threadIdx.x;               // < 115712 exactly
        int T = i >> 9, t2 = i & 511;
        int j = t2 & 7, l = (t2 >> 3) & 63;
        int g = l >> 5, o = l & 31;
        int layer, cls, t;                           // cls: 0 real, 1 self
        if (T < 17)       { layer = 0; cls = 0; t = T; }
        else if (T < 19)  { layer = 0; cls = 1; t = T - 17; }
        else if (T < 85)  { layer = 1; cls = 0; t = T - 19; }
        else if (T < 88)  { layer = 1; cls = 1; t = T - 85; }
        else if (T < 154) { layer = 2; cls = 0; t = T - 88; }
        else if (T < 157) { layer = 2; cls = 1; t = T - 154; }
        else if (T < 223) { layer = 3; cls = 0; t = T - 157; }
        else              { layer = 3; cls = 1; t = T - 223; }
        const int INP   = (layer == 0) ? 8 : 32;
        const int IN_C  = (layer == 0) ? 6 : 32;
        const int OUT_C = (layer == 3) ? 2 : 32;
        float v = 0.f;
        if (cls == 0) {
            const int S_MAIN = 2 * INP;
            if (t < S_MAIN) {
                int kap = 16 * t + 8 * g + j;
                int k  = (INP == 8) ? (kap >> 3) : (kap >> 5);
                int ii = (INP == 8) ? (kap & 7)  : (kap & 31);
                if (ii < IN_C && o < OUT_C)
                    v = p.w2[layer][(size_t)k * (IN_C * OUT_C) + ii * OUT_C + o];
            } else {
                int ii = 16 * (t - S_MAIN) + 8 * g + j;
                if (ii < IN_C && o < OUT_C)
                    v = p.b2[layer][ii * OUT_C + o];
            }
        } else {
            const int nroot = (layer == 0) ? 1 : 2;
            if (t < nroot) {
                int ii = 16 * t + 8 * g + j;
                if (ii < IN_C && o < OUT_C)
                    v = p.root[layer][ii * OUT_C + o];
            } else {
                if (g == 0 && j == 0 && o < OUT_C)
                    v = p.bias[layer][o];
            }
        }
        p.bswz[i] = (_Float16)v;
    } else if (b < 452 + NB8) {                      // ---- pack xin ----
        int i = (b - 452) * 256 + threadIdx.x;
        if (i < p.N * 8) {
            int v = i >> 3, c = i & 7;
            float val = (c < 6) ? p.x[(size_t)v * 10 + 4 + c] : 0.f;
            p.xin[i] = (_Float16)val;
        }
    } else if (b < 452 + NB8 + NZA) {                // ---- zero agg0..2 ----
        long long i = (long long)(b - 452 - NB8) * 256 + threadIdx.x;
        if (i < (long long)p.N * 12)                 // 3*N*32*2B / 16B
            ((uint4*)p.aggz)[i] = uint4{0u, 0u, 0u, 0u};
    } else if (b < 452 + NB8 + NZA + NZO) {          // ---- zero out ----
        int v = (b - 452 - NB8 - NZA) * 256 + threadIdx.x;
        if (v < p.N)
            ((float2*)p.outz)[v] = float2{0.f, 0.f};
    } else {                                         // ---- w1h / b1h ----
        for (int i = threadIdx.x; i < W1H_TOT; i += 256) {   // FIX: cover 640
            int layer = i / 160, r = i % 160;
            float v = (r < 128) ? p.w1[layer][r]     // w1 row-major (4,32)
                                : p.b1[layer][r - 128];
            p.w1h[i] = (_Float16)v;
        }
    }
}

// gather 32 f16 feats for node s, relu in packed f16
static __device__ __forceinline__ void gather32h(
    const _Float16* __restrict__ fprev, int s, int g, half8v& xh0, half8v& xh1)
{
    const half8v* fp = (const half8v*)(fprev + (size_t)s * 32);
    xh0 = fp[g];
    xh1 = fp[2 + g];
    #pragma unroll
    for (int j = 0; j < 8; ++j) {
        xh0[j] = xh0[j] > (_Float16)0.f ? xh0[j] : (_Float16)0.f;
        xh1[j] = xh1[j] > (_Float16)0.f ? xh1[j] : (_Float16)0.f;
    }
}

// splat one f16 value into all 8 lanes of a half8v
static __device__ __forceinline__ half8v splat8(_Float16 h)
{
    half8v r;
    #pragma unroll
    for (int j = 0; j < 8; ++j) r[j] = h;
    return r;
}

// paired pk-f16 atomic: lanes o and o^1 hold the same row, cols o / o^1.
static __device__ __forceinline__ void pk_atomic_row(
    _Float16* __restrict__ aggH, int row, int o, float mine)
{
    float oth = __shfl_xor(mine, 1);
    if ((o & 1) == 0 && row >= 0) {
        __half2 v = __floats2half2_rn(mine, oth);
        unsafeAtomicAdd((__half2*)aggH + (((size_t)row << 5) + o) / 2, v);
    }
}

// ---------------------------------------------------------------------------
// Edge kernel (R14 structure: 1024-thread blocks, 32 waves/CU, LDS-staged B,
// pk-f16 atomics) with PACKED f16 h-chain using native f16 vectors:
// h2 = max(fma2 x4) — v_pk_fma_f16/v_pk_max_f16, 5 packed ops per TWO k.
// C layout: col = lane&31, row = (r&3)+8*(r>>2)+4*(lane>>5).
// ---------------------------------------------------------------------------
template<int INP, int OUT_C>
__global__ __launch_bounds__(1024, 8) void edge(
    const _Float16* __restrict__ xin,     // layer0 features (N x 8)
    const _Float16* __restrict__ fprev,   // mid features (N x 32 f16, pre-relu)
    const int*      __restrict__ src,
    const int*      __restrict__ dst,
    const float*    __restrict__ ea,
    const _Float16* __restrict__ w1h,     // 160 f16: w1 pairs (4x16 half2v) + b1 (16 half2v)
    const _Float16* __restrict__ bAll,    // real || self fragments, contiguous
    _Float16* __restrict__ aggH,          // N x 32 f16 (OUT_C==32)
    float*    __restrict__ aggF,          // N x 2 f32  (OUT_C==2)
    int E, int N, int ntileE, int ntot)
{
    constexpr int NREAL = (INP == 32) ? 66 : 17;
    constexpr int NSELF = (INP == 32) ? 3  : 2;
    constexpr int NSTEP = NREAL + NSELF;

    __shared__ half8v ldsb[NSTEP * 64];
    {
        const half8v* bp = (const half8v*)bAll;
        for (int i = threadIdx.x; i < NSTEP * 64; i += 1024)
            ldsb[i] = bp[i];
    }
    __syncthreads();

    const int lane = threadIdx.x & 63;
    const int g = lane >> 5, o = lane & 31;
    const int lrow = lane & 31;
    const int wv = (blockIdx.x * 1024 + threadIdx.x) >> 6;
    const int nw = gridDim.x * 16;

    const half2v* w1p = (const half2v*)w1h;          // row*16 + t
    const half2v* b1p = (const half2v*)(w1h + 128);
    const half2v zero2 = { (_Float16)0.f, (_Float16)0.f };

    half8v ones;
    #pragma unroll
    for (int j = 0; j < 8; ++j) ones[j] = (_Float16)0.f;
    ones[0] = (_Float16)1.f;

    for (int tile = wv; tile < ntot; tile += nw) {
        f32x16 C;
        #pragma unroll
        for (int i = 0; i < 16; ++i) C[i] = 0.f;

        if (tile < ntileE) {
            // ================= real edges =================
            const int e0 = tile * 32;
            const int er = e0 + lrow;
            const int ec = er < E ? er : (E - 1);
            const int s  = src[ec];
            const float4 av = *(const float4*)(ea + 4ll * ec);
            half2v eax; eax[0] = (_Float16)av.x; eax[1] = eax[0];
            half2v eay; eay[0] = (_Float16)av.y; eay[1] = eay[0];
            half2v eaz; eaz[0] = (_Float16)av.z; eaz[1] = eaz[0];
            half2v eaw; eaw[0] = (_Float16)av.w; eaw[1] = eaw[0];

            half8v xh0, xh1;
            if constexpr (INP == 32) gather32h(fprev, s, g, xh0, xh1);
            else                     xh0 = *(const half8v*)(xin + (size_t)s * 8);

            if constexpr (INP == 32) {
                #pragma unroll 2
                for (int t = 0; t < 16; ++t) {       // k-pair (2t, 2t+1)
                    half2v h2 = eax * w1p[t] + b1p[t];        // v_pk_fma_f16
                    h2 = eay * w1p[16 + t] + h2;
                    h2 = eaz * w1p[32 + t] + h2;
                    h2 = eaw * w1p[48 + t] + h2;
                    h2 = __builtin_elementwise_max(h2, zero2); // v_pk_max_f16
                    half8v hsl = splat8(h2[0]);
                    half8v hsh = splat8(h2[1]);
                    half8v bf0 = ldsb[(4*t    ) * 64 + lane];
                    half8v bf1 = ldsb[(4*t + 1) * 64 + lane];
                    half8v bf2 = ldsb[(4*t + 2) * 64 + lane];
                    half8v bf3 = ldsb[(4*t + 3) * 64 + lane];
                    C = __builtin_amdgcn_mfma_f32_32x32x16_f16(hsl * xh0, bf0, C, 0, 0, 0);
                    C = __builtin_amdgcn_mfma_f32_32x32x16_f16(hsl * xh1, bf1, C, 0, 0, 0);
                    C = __builtin_amdgcn_mfma_f32_32x32x16_f16(hsh * xh0, bf2, C, 0, 0, 0);
                    C = __builtin_amdgcn_mfma_f32_32x32x16_f16(hsh * xh1, bf3, C, 0, 0, 0);
                }
                C = __builtin_amdgcn_mfma_f32_32x32x16_f16(xh0, ldsb[64*64 + lane], C, 0, 0, 0);
                C = __builtin_amdgcn_mfma_f32_32x32x16_f16(xh1, ldsb[65*64 + lane], C, 0, 0, 0);
            } else {
                #pragma unroll 4
                for (int t = 0; t < 16; ++t) {       // k = 2t + g (lane-dep)
                    half2v h2 = eax * w1p[t] + b1p[t];
                    h2 = eay * w1p[16 + t] + h2;
                    h2 = eaz * w1p[32 + t] + h2;
                    h2 = eaw * w1p[48 + t] + h2;
                    h2 = __builtin_elementwise_max(h2, zero2);
                    half8v hs = splat8(g ? h2[1] : h2[0]);
                    half8v bf = ldsb[t * 64 + lane];
                    C = __builtin_amdgcn_mfma_f32_32x32x16_f16(hs * xh0, bf, C, 0, 0, 0);
                }
                half8v zz;
                #pragma unroll
                for (int j = 0; j < 8; ++j) zz[j] = (_Float16)0.f;
                half8v a = (g == 0) ? xh0 : zz;      // b2 tail
                C = __builtin_amdgcn_mfma_f32_32x32x16_f16(a, ldsb[16*64 + lane], C, 0, 0, 0);
            }

            // epilogue: reg 4q+m -> edge row e0+8q+4g+m, col o
            if constexpr (OUT_C == 32) {
                #pragma unroll
                for (int q = 0; q < 4; ++q) {
                    const int eb = e0 + 8 * q + 4 * g;
                    int rows[4];
                    if (eb + 3 < E) {
                        const int4 dd = *(const int4*)(dst + eb);
                        rows[0] = dd.x; rows[1] = dd.y; rows[2] = dd.z; rows[3] = dd.w;
                    } else {
                        #pragma unroll
                        for (int m = 0; m < 4; ++m)
                            rows[m] = (eb + m < E) ? dst[eb + m] : -1;
                    }
                    #pragma unroll
                    for (int m = 0; m < 4; ++m)
                        pk_atomic_row(aggH, rows[m], o, C[4*q + m]);
                }
            } else {
                if (o < OUT_C) {
                    #pragma unroll
                    for (int q = 0; q < 4; ++q) {
                        const int eb = e0 + 8 * q + 4 * g;
                        #pragma unroll
                        for (int m = 0; m < 4; ++m)
                            if (eb + m < E)
                                unsafeAtomicAdd(aggF + (size_t)dst[eb + m] * OUT_C + o,
                                                C[4*q + m]);
                    }
                }
            }
        } else {
            // ================= self edges (node term) =================
            const int v0 = (tile - ntileE) * 32;
            const int vr = v0 + lrow;
            const int vc = vr < N ? vr : (N - 1);

            if constexpr (INP == 32) {
                half8v xh0, xh1;
                gather32h(fprev, vc, g, xh0, xh1);
                C = __builtin_amdgcn_mfma_f32_32x32x16_f16(xh0,  ldsb[(NREAL+0)*64 + lane], C, 0, 0, 0);
                C = __builtin_amdgcn_mfma_f32_32x32x16_f16(xh1,  ldsb[(NREAL+1)*64 + lane], C, 0, 0, 0);
                C = __builtin_amdgcn_mfma_f32_32x32x16_f16(ones, ldsb[(NREAL+2)*64 + lane], C, 0, 0, 0);
            } else {
                half8v xh0 = *(const half8v*)(xin + (size_t)vc * 8);
                C = __builtin_amdgcn_mfma_f32_32x32x16_f16(xh0,  ldsb[(NREAL+0)*64 + lane], C, 0, 0, 0);
                C = __builtin_amdgcn_mfma_f32_32x32x16_f16(ones, ldsb[(NREAL+1)*64 + lane], C, 0, 0, 0);
            }

            if constexpr (OUT_C == 32) {
                #pragma unroll
                for (int q = 0; q < 4; ++q) {
                    #pragma unroll
                    for (int m = 0; m < 4; ++m) {
                        const int row = v0 + 8*q + 4*g + m;
                        pk_atomic_row(aggH, row < N ? row : -1, o, C[4*q + m]);
                    }
                }
            } else {
                if (o < OUT_C) {
                    #pragma unroll
                    for (int q = 0; q < 4; ++q) {
                        #pragma unroll
                        for (int m = 0; m < 4; ++m) {
                            const int row = v0 + 8*q + 4*g + m;
                            if (row < N)
                                unsafeAtomicAdd(aggF + (size_t)row * OUT_C + o, C[4*q + m]);
                        }
                    }
                }
            }
        }
    }
}

// ---------------------------------------------------------------------------
extern "C" void kernel_launch(void* const* d_in, const int* in_sizes, int n_in,
                              void* d_out, int out_size, void* d_ws, size_t ws_size,
                              hipStream_t stream)
{
    const float* x  = (const float*)d_in[0];
    const int*   ei = (const int*)d_in[1];
    const float* ea = (const float*)d_in[2];

    const int E = in_sizes[2] / 4;
    const int N = in_sizes[0] / 10;
    const int* src = ei;
    const int* dst = ei + E;

    const float* p[4][6];   // w1, b1, w2, b2, root, bias
    for (int L = 0; L < 4; ++L)
        for (int j = 0; j < 6; ++j)
            p[L][j] = (const float*)d_in[3 + 6 * L + j];

    char* w = (char*)d_ws;
    auto carve = [&](size_t bytes) {
        char* q = w; w += (bytes + 255) & ~(size_t)255; return (void*)q;
    };
    _Float16* xin  = (_Float16*)carve((size_t)N * 8 * 2);
    _Float16* aggz = (_Float16*)carve((size_t)3 * N * 32 * 2); // agg0|agg1|agg2 f16
    _Float16* bswz = (_Float16*)carve((size_t)BSWZ_TOT * 2);
    _Float16* w1hb = (_Float16*)carve((size_t)W1H_TOT * 2);
    _Float16* agg0 = aggz;
    _Float16* agg1 = aggz + (size_t)N * 32;
    _Float16* agg2 = aggz + (size_t)2 * N * 32;
    float* out  = (float*)d_out;

    Prm prm{};
    prm.x = x;
    for (int L = 0; L < 4; ++L) {
        prm.w1[L] = p[L][0]; prm.b1[L] = p[L][1];
        prm.w2[L] = p[L][2]; prm.b2[L] = p[L][3];
        prm.root[L] = p[L][4]; prm.bias[L] = p[L][5];
    }
    prm.xin = xin; prm.bswz = bswz; prm.w1h = w1hb;
    prm.aggz = aggz; prm.outz = out; prm.N = N;

    const int NB8 = (N * 8 + 255) / 256;
    const int NZA = (N * 12 + 255) / 256;            // 3*N*32*2B / 16B uint4
    const int NZO = (N + 255) / 256;                 // N float2

    const int ntileE = (E + 31) / 32;
    const int ntileN = (N + 31) / 32;
    const int ntot   = ntileE + ntileN;
    int NB = (ntot + 15) / 16;                       // 16 waves / block
    if (NB > 512) NB = 512;                          // 2 blocks/CU co-resident

    // 5 dispatches total
    prep<<<452 + NB8 + NZA + NZO + 1, 256, 0, stream>>>(prm, NB8, NZA, NZO);

    edge<8, 32><<<NB, 1024, 0, stream>>>(            // layer 0
        xin, nullptr, src, dst, ea, w1hb + 0 * 160,
        bswz + 0 * 512, agg0, nullptr, E, N, ntileE, ntot);

    edge<32, 32><<<NB, 1024, 0, stream>>>(           // layer 1
        nullptr, agg0, src, dst, ea, w1hb + 1 * 160,
        bswz + 19 * 512, agg1, nullptr, E, N, ntileE, ntot);

    edge<32, 32><<<NB, 1024, 0, stream>>>(           // layer 2
        nullptr, agg1, src, dst, ea, w1hb + 2 * 160,
        bswz + 88 * 512, agg2, nullptr, E, N, ntileE, ntot);

    edge<32, 2><<<NB, 1024, 0, stream>>>(            // layer 3 -> d_out
        nullptr, agg2, src, dst, ea, w1hb + 3 * 160,
        bswz + 157 * 512, nullptr, out, E, N, ntileE, ntot);
}